// Round 8
// baseline (130.323 us; speedup 1.0000x reference)
//
#include <hip/hip_runtime.h>

#define CCH 256
#define HIDN 64
#define NB  8
#define NHW 4096

// ws layout (dwords): w1pk[16384] | w2pk[9216]  (= 100 KB)
#define W1PK_OFF 0
#define W2PK_OFF 16384

typedef __attribute__((ext_vector_type(8))) short bf16x8;
typedef __attribute__((ext_vector_type(4))) float f32x4;
typedef __attribute__((ext_vector_type(4))) int   i32x4;
typedef __attribute__((ext_vector_type(2))) int   i32x2;

__device__ __forceinline__ unsigned short bf16_rne(float f) {
    unsigned u = __float_as_uint(f);
    u += 0x7FFFu + ((u >> 16) & 1u);
    return (unsigned short)(u >> 16);
}
__device__ __forceinline__ float bf16_f32(unsigned short s) {
    return __uint_as_float(((unsigned)s) << 16);
}
__device__ __forceinline__ bf16x8 as_bf16(i32x4 v) {
    union { i32x4 i; bf16x8 b; } u; u.i = v; return u.b;
}

// ---------------------------------------------------------------------------
// Prepack weights into MFMA A-fragment order, split hi/lo bf16.
// Fragment map (assumed, consistent with B-side reads — see kernel):
//   elem ei of lane l: m = mt*16 + (l&15); k = ks*32 + (ei>>2)*16 + ((l>>4)&3)*4 + (ei&3)
// w1pk dword idx = ot*4096 + ks*512 + pass*256 + lane*4 + d   (ot<4, ks<8)
// w2pk dword idx = jt*1024 + ks*512 + pass*256 + lane*4 + d   (jt<9, ks<2)
// ---------------------------------------------------------------------------
__global__ __launch_bounds__(256) void prepack_kernel(
    const float* __restrict__ w_reduce, const float* __restrict__ w_span,
    unsigned* __restrict__ ws)
{
    const int idx = blockIdx.x * 256 + threadIdx.x;   // 100*256 = 25600
    int d, lane, pass, ks, mt, K, base;
    const float* W;
    if (idx < 16384) {
        d = idx & 3; lane = (idx >> 2) & 63; pass = (idx >> 8) & 1;
        ks = (idx >> 9) & 7; mt = (idx >> 12) & 3;
        W = w_reduce; K = 256; base = W1PK_OFF + idx;
    } else {
        const int i2 = idx - 16384;
        d = i2 & 3; lane = (i2 >> 2) & 63; pass = (i2 >> 8) & 1;
        ks = (i2 >> 9) & 1; mt = i2 >> 10;
        W = w_span; K = 64; base = W2PK_OFF + i2;
    }
    const int m = mt * 16 + (lane & 15);
    const int g = (lane >> 4) & 3;
    unsigned o = 0;
    #pragma unroll
    for (int h = 0; h < 2; ++h) {
        const int ei = d * 2 + h;
        const int k  = ks * 32 + ((ei >> 2) << 4) + (g << 2) + (ei & 3);
        const float w = W[m * K + k];
        const unsigned short hi = bf16_rne(w);
        const unsigned short v  = pass ? bf16_rne(w - bf16_f32(hi)) : hi;
        o |= ((unsigned)v) << (16 * h);
    }
    ws[base] = o;
}

// ---------------------------------------------------------------------------
// Fused involution, MFMA gen. Block = 512 thr (8 waves) = one image row.
// LDS (34304 B): phase1 xT[px][134dw]; after barrier: hT dw[0,2432),
//                kls (bf16 kmap[j][66]) shorts [4864, 14368).
// ---------------------------------------------------------------------------
__global__ __launch_bounds__(512, 6) void invol_fused(
    const float* __restrict__ x,        // [B,256,64,64]
    const float* __restrict__ b_reduce, // [64]
    const float* __restrict__ b_span,   // [144]
    const unsigned* __restrict__ wpk,   // w1pk/w2pk
    float* __restrict__ out)            // [B,256,64,64]
{
    __shared__ __align__(16) int lds[8576];
    short* const lds_s = (short*)lds;

    const int tid  = threadIdx.x;
    const int lane = tid & 63;
    const int wid  = __builtin_amdgcn_readfirstlane(tid >> 6);
    const int n    = lane & 15;
    const int g    = lane >> 4;

    const int raw = blockIdx.x;                    // [0,512)
    const int row = ((raw & 7) << 6) | (raw >> 3); // XCD chunk swizzle
    const int b   = row >> 6;
    const int hr  = row & 63;

    const float* xb = x + (size_t)b * (CCH * NHW) + hr * 64;

    // ---- stage x row -> bf16 xT[px][c]  (dw stride 134 == 6 mod 32) ----
    {
        const int px = tid & 63;
        const int c0 = (tid >> 6) * 32;
        const float* xp = xb + (size_t)c0 * NHW + px;
        int* dst = &lds[px * 134 + (c0 >> 1)];
        #pragma unroll
        for (int i = 0; i < 16; ++i) {
            const float f0 = xp[(2 * i) * NHW];
            const float f1 = xp[(2 * i + 1) * NHW];
            dst[i] = (int)((unsigned)bf16_rne(f0) |
                           ((unsigned)bf16_rne(f1) << 16));
        }
    }
    __syncthreads();

    // ---- phase 1: hid = relu(W1*x + b1) via MFMA (W1 = hi + lo) ----
    const int ot  = wid >> 1;          // o-tile
    const int pt0 = (wid & 1) * 2;     // first px-tile of 2
    f32x4 acc0 = {0.f, 0.f, 0.f, 0.f};
    f32x4 acc1 = {0.f, 0.f, 0.f, 0.f};
    const int* w1pk = (const int*)wpk + W1PK_OFF;

    #pragma unroll
    for (int ks = 0; ks < 8; ++ks) {
        const int abase = ot * 4096 + ks * 512 + lane * 4;
        const i32x4 ah = *(const i32x4*)(w1pk + abase);        // pass 0 (hi)
        const i32x4 al = *(const i32x4*)(w1pk + abase + 256);  // pass 1 (lo)
        const int bb0 = (pt0 * 16 + n) * 134 + ks * 16 + g * 2;
        const int bb1 = bb0 + 16 * 134;
        const i32x2 p0 = *(const i32x2*)&lds[bb0];
        const i32x2 p1 = *(const i32x2*)&lds[bb0 + 8];
        const i32x2 q0 = *(const i32x2*)&lds[bb1];
        const i32x2 q1 = *(const i32x2*)&lds[bb1 + 8];
        const i32x4 b0 = {p0.x, p0.y, p1.x, p1.y};
        const i32x4 b1 = {q0.x, q0.y, q1.x, q1.y};
        const bf16x8 fa_h = as_bf16(ah), fa_l = as_bf16(al);
        const bf16x8 fb0 = as_bf16(b0), fb1 = as_bf16(b1);
        acc0 = __builtin_amdgcn_mfma_f32_16x16x32_bf16(fa_h, fb0, acc0, 0, 0, 0);
        acc0 = __builtin_amdgcn_mfma_f32_16x16x32_bf16(fa_l, fb0, acc0, 0, 0, 0);
        acc1 = __builtin_amdgcn_mfma_f32_16x16x32_bf16(fa_h, fb1, acc1, 0, 0, 0);
        acc1 = __builtin_amdgcn_mfma_f32_16x16x32_bf16(fa_l, fb1, acc1, 0, 0, 0);
    }
    __syncthreads();                   // all xT reads done -> region reusable

    // ---- bias + relu -> hT[px][o] bf16 (dw stride 38 == 6 mod 32) ----
    {
        const f32x4 br = *(const f32x4*)&b_reduce[ot * 16 + g * 4];
        const unsigned h00 = (unsigned)bf16_rne(fmaxf(acc0.x + br.x, 0.f))
                           | ((unsigned)bf16_rne(fmaxf(acc0.y + br.y, 0.f)) << 16);
        const unsigned h01 = (unsigned)bf16_rne(fmaxf(acc0.z + br.z, 0.f))
                           | ((unsigned)bf16_rne(fmaxf(acc0.w + br.w, 0.f)) << 16);
        const unsigned h10 = (unsigned)bf16_rne(fmaxf(acc1.x + br.x, 0.f))
                           | ((unsigned)bf16_rne(fmaxf(acc1.y + br.y, 0.f)) << 16);
        const unsigned h11 = (unsigned)bf16_rne(fmaxf(acc1.z + br.z, 0.f))
                           | ((unsigned)bf16_rne(fmaxf(acc1.w + br.w, 0.f)) << 16);
        const i32x2 w0 = {(int)h00, (int)h01};
        const i32x2 w1 = {(int)h10, (int)h11};
        *(i32x2*)&lds[(pt0 * 16 + n) * 38 + ot * 8 + g * 2]       = w0;
        *(i32x2*)&lds[((pt0 + 1) * 16 + n) * 38 + ot * 8 + g * 2] = w1;
    }
    __syncthreads();

    // ---- phase 2: kmap = W2*hid + b2 -> kls[j][px] bf16 ----
    const int* w2pk = (const int*)wpk + W2PK_OFF;
    for (int t = wid; t < 36; t += 8) {            // 9 j-tiles x 4 px-tiles
        const int jt = t >> 2, pt = t & 3;
        f32x4 acc = {0.f, 0.f, 0.f, 0.f};
        #pragma unroll
        for (int ks = 0; ks < 2; ++ks) {
            const int abase = jt * 1024 + ks * 512 + lane * 4;
            const i32x4 ah = *(const i32x4*)(w2pk + abase);
            const i32x4 al = *(const i32x4*)(w2pk + abase + 256);
            const int bb = (pt * 16 + n) * 38 + ks * 16 + g * 2;
            const i32x2 p0 = *(const i32x2*)&lds[bb];
            const i32x2 p1 = *(const i32x2*)&lds[bb + 8];
            const i32x4 bi = {p0.x, p0.y, p1.x, p1.y};
            const bf16x8 fb = as_bf16(bi);
            acc = __builtin_amdgcn_mfma_f32_16x16x32_bf16(as_bf16(ah), fb, acc, 0, 0, 0);
            acc = __builtin_amdgcn_mfma_f32_16x16x32_bf16(as_bf16(al), fb, acc, 0, 0, 0);
        }
        const f32x4 bs = *(const f32x4*)&b_span[jt * 16 + g * 4];
        const int jb = jt * 16 + g * 4;
        const int pxi = pt * 16 + n;
        lds_s[4864 + (jb + 0) * 66 + pxi] = (short)bf16_rne(acc.x + bs.x);
        lds_s[4864 + (jb + 1) * 66 + pxi] = (short)bf16_rne(acc.y + bs.y);
        lds_s[4864 + (jb + 2) * 66 + pxi] = (short)bf16_rne(acc.z + bs.z);
        lds_s[4864 + (jb + 3) * 66 + pxi] = (short)bf16_rne(acc.w + bs.w);
    }
    __syncthreads();

    // ---- apply: 32 channels (groups {2w,2w+1}) per wave, fp32 taps ----
    const bool vwm = (lane > 0), vwp = (lane < 63);
    const bool vhm = (hr  > 0), vhp = (hr  < 63);
    const bool vk[9] = { vhm && vwm, vhm, vhm && vwp,
                         vwm,        true, vwp,
                         vhp && vwm, vhp, vhp && vwp };
    float kv[18];
    #pragma unroll
    for (int jj = 0; jj < 18; ++jj) {
        const float v = bf16_f32((unsigned short)
                        lds_s[4864 + (wid * 18 + jj) * 66 + lane]);
        kv[jj] = vk[jj % 9] ? v : 0.f;
    }
    const int oWm = vwm ? -1  : 0, oWp = vwp ? 1  : 0;
    const int oHm = vhm ? -64 : 0, oHp = vhp ? 64 : 0;
    const int oo[9] = { oHm + oWm, oHm, oHm + oWp,
                        oWm,       0,   oWp,
                        oHp + oWm, oHp, oHp + oWp };

    const float* xrow = xb + lane;
    float*       orow = out + (size_t)b * (CCH * NHW) + hr * 64 + lane;

    #pragma unroll 4
    for (int m = 0; m < 32; ++m) {
        const int c  = wid * 32 + m;
        const int gl = m >> 4;
        const float* xc = xrow + (size_t)c * NHW;
        float a = 0.f;
        #pragma unroll
        for (int k = 0; k < 9; ++k)
            a = fmaf(xc[oo[k]], kv[gl * 9 + k], a);
        orow[(size_t)c * NHW] = a;
    }
}

// ---------------------------------------------------------------------------
extern "C" void kernel_launch(void* const* d_in, const int* in_sizes, int n_in,
                              void* d_out, int out_size, void* d_ws, size_t ws_size,
                              hipStream_t stream) {
    const float* x        = (const float*)d_in[0];
    const float* w_reduce = (const float*)d_in[1];
    const float* b_reduce = (const float*)d_in[2];
    const float* w_span   = (const float*)d_in[3];
    const float* b_span   = (const float*)d_in[4];
    float* out = (float*)d_out;
    unsigned* ws = (unsigned*)d_ws;    // 100 KB used

    prepack_kernel<<<dim3(100), dim3(256), 0, stream>>>(w_reduce, w_span, ws);
    invol_fused<<<dim3(NB * 64), dim3(512), 0, stream>>>(
        x, b_reduce, b_span, ws, out);
}

// Round 9
// 104.668 us; speedup vs baseline: 1.2451x; 1.2451x over previous
//
#include <hip/hip_runtime.h>

#define CCH 256
#define HIDN 64
#define NB  8
#define NHW 4096

// ws layout (dwords): w1pk[16384] | w2pk[9216]  (= 100 KB)
#define W1PK_OFF 0
#define W2PK_OFF 16384

typedef __attribute__((ext_vector_type(8))) short bf16x8;
typedef __attribute__((ext_vector_type(4))) float f32x4;
typedef __attribute__((ext_vector_type(4))) int   i32x4;
typedef __attribute__((ext_vector_type(2))) int   i32x2;

__device__ __forceinline__ unsigned short bf16_rne(float f) {
    unsigned u = __float_as_uint(f);
    u += 0x7FFFu + ((u >> 16) & 1u);
    return (unsigned short)(u >> 16);
}
__device__ __forceinline__ float bf16_f32(unsigned short s) {
    return __uint_as_float(((unsigned)s) << 16);
}
__device__ __forceinline__ bf16x8 as_bf16(i32x4 v) {
    union { i32x4 i; bf16x8 b; } u; u.i = v; return u.b;
}

// ---------------------------------------------------------------------------
// Prepack weights into MFMA A-fragment order, split hi/lo bf16.
//   elem ei of lane l: m = mt*16 + (l&15); k = ks*32 + (ei>>2)*16 + ((l>>4)&3)*4 + (ei&3)
// w1pk dword idx = ot*4096 + ks*512 + pass*256 + lane*4 + d   (ot<4, ks<8)
// w2pk dword idx = jt*1024 + ks*512 + pass*256 + lane*4 + d   (jt<9, ks<2)
// ---------------------------------------------------------------------------
__global__ __launch_bounds__(256) void prepack_kernel(
    const float* __restrict__ w_reduce, const float* __restrict__ w_span,
    unsigned* __restrict__ ws)
{
    const int idx = blockIdx.x * 256 + threadIdx.x;   // 100*256 = 25600
    int d, lane, pass, ks, mt, K, base;
    const float* W;
    if (idx < 16384) {
        d = idx & 3; lane = (idx >> 2) & 63; pass = (idx >> 8) & 1;
        ks = (idx >> 9) & 7; mt = (idx >> 12) & 3;
        W = w_reduce; K = 256; base = W1PK_OFF + idx;
    } else {
        const int i2 = idx - 16384;
        d = i2 & 3; lane = (i2 >> 2) & 63; pass = (i2 >> 8) & 1;
        ks = (i2 >> 9) & 1; mt = i2 >> 10;
        W = w_span; K = 64; base = W2PK_OFF + i2;
    }
    const int m = mt * 16 + (lane & 15);
    const int g = (lane >> 4) & 3;
    unsigned o = 0;
    #pragma unroll
    for (int h = 0; h < 2; ++h) {
        const int ei = d * 2 + h;
        const int k  = ks * 32 + ((ei >> 2) << 4) + (g << 2) + (ei & 3);
        const float w = W[m * K + k];
        const unsigned short hi = bf16_rne(w);
        const unsigned short v  = pass ? bf16_rne(w - bf16_f32(hi)) : hi;
        o |= ((unsigned)v) << (16 * h);
    }
    ws[base] = o;
}

// ---------------------------------------------------------------------------
// Fused involution, MFMA gen. Block = 512 thr (8 waves) = one image row.
// LDS (34304 B): phase1 xT[px][134dw]; after barrier: hT dw[0,2432),
//                kls (bf16 kmap[j][66]) shorts [4864, 14368).
// ---------------------------------------------------------------------------
__global__ __launch_bounds__(512, 4) void invol_fused(
    const float* __restrict__ x,        // [B,256,64,64]
    const float* __restrict__ b_reduce, // [64]
    const float* __restrict__ b_span,   // [144]
    const unsigned* __restrict__ wpk,   // w1pk/w2pk
    float* __restrict__ out)            // [B,256,64,64]
{
    __shared__ __align__(16) int lds[8576];
    short* const lds_s = (short*)lds;

    const int tid  = threadIdx.x;
    const int lane = tid & 63;
    const int wid  = __builtin_amdgcn_readfirstlane(tid >> 6);
    const int n    = lane & 15;
    const int g    = lane >> 4;

    const int raw = blockIdx.x;                    // [0,512)
    const int row = ((raw & 7) << 6) | (raw >> 3); // XCD chunk swizzle
    const int b   = row >> 6;
    const int hr  = row & 63;

    const float* xb = x + (size_t)b * (CCH * NHW) + hr * 64;

    // ---- stage x row -> bf16 xT[px][c]  (dw stride 134 == 6 mod 32) ----
    {
        const int px = tid & 63;
        const int c0 = (tid >> 6) * 32;
        const float* xp = xb + (size_t)c0 * NHW + px;
        int* dst = &lds[px * 134 + (c0 >> 1)];
        #pragma unroll
        for (int i = 0; i < 16; ++i) {
            const float f0 = xp[(2 * i) * NHW];
            const float f1 = xp[(2 * i + 1) * NHW];
            dst[i] = (int)((unsigned)bf16_rne(f0) |
                           ((unsigned)bf16_rne(f1) << 16));
        }
    }
    __syncthreads();

    // ---- phase 1: hid = relu(W1*x + b1) via MFMA (W1 = hi + lo) ----
    const int ot  = wid >> 1;          // o-tile
    const int pt0 = (wid & 1) * 2;     // first px-tile of 2
    f32x4 acc0 = {0.f, 0.f, 0.f, 0.f};
    f32x4 acc1 = {0.f, 0.f, 0.f, 0.f};
    const int* w1pk = (const int*)wpk + W1PK_OFF;

    #pragma unroll
    for (int ks = 0; ks < 8; ++ks) {
        const int abase = ot * 4096 + ks * 512 + lane * 4;
        const i32x4 ah = *(const i32x4*)(w1pk + abase);        // pass 0 (hi)
        const i32x4 al = *(const i32x4*)(w1pk + abase + 256);  // pass 1 (lo)
        const int bb0 = (pt0 * 16 + n) * 134 + ks * 16 + g * 2;
        const int bb1 = bb0 + 16 * 134;
        const i32x2 p0 = *(const i32x2*)&lds[bb0];
        const i32x2 p1 = *(const i32x2*)&lds[bb0 + 8];
        const i32x2 q0 = *(const i32x2*)&lds[bb1];
        const i32x2 q1 = *(const i32x2*)&lds[bb1 + 8];
        const i32x4 b0 = {p0.x, p0.y, p1.x, p1.y};
        const i32x4 b1 = {q0.x, q0.y, q1.x, q1.y};
        const bf16x8 fa_h = as_bf16(ah), fa_l = as_bf16(al);
        const bf16x8 fb0 = as_bf16(b0), fb1 = as_bf16(b1);
        acc0 = __builtin_amdgcn_mfma_f32_16x16x32_bf16(fa_h, fb0, acc0, 0, 0, 0);
        acc0 = __builtin_amdgcn_mfma_f32_16x16x32_bf16(fa_l, fb0, acc0, 0, 0, 0);
        acc1 = __builtin_amdgcn_mfma_f32_16x16x32_bf16(fa_h, fb1, acc1, 0, 0, 0);
        acc1 = __builtin_amdgcn_mfma_f32_16x16x32_bf16(fa_l, fb1, acc1, 0, 0, 0);
    }
    __syncthreads();                   // all xT reads done -> region reusable

    // ---- bias + relu -> hT[px][o] bf16 (dw stride 38 == 6 mod 32) ----
    {
        const f32x4 br = *(const f32x4*)&b_reduce[ot * 16 + g * 4];
        const unsigned h00 = (unsigned)bf16_rne(fmaxf(acc0.x + br.x, 0.f))
                           | ((unsigned)bf16_rne(fmaxf(acc0.y + br.y, 0.f)) << 16);
        const unsigned h01 = (unsigned)bf16_rne(fmaxf(acc0.z + br.z, 0.f))
                           | ((unsigned)bf16_rne(fmaxf(acc0.w + br.w, 0.f)) << 16);
        const unsigned h10 = (unsigned)bf16_rne(fmaxf(acc1.x + br.x, 0.f))
                           | ((unsigned)bf16_rne(fmaxf(acc1.y + br.y, 0.f)) << 16);
        const unsigned h11 = (unsigned)bf16_rne(fmaxf(acc1.z + br.z, 0.f))
                           | ((unsigned)bf16_rne(fmaxf(acc1.w + br.w, 0.f)) << 16);
        const i32x2 w0 = {(int)h00, (int)h01};
        const i32x2 w1 = {(int)h10, (int)h11};
        *(i32x2*)&lds[(pt0 * 16 + n) * 38 + ot * 8 + g * 2]       = w0;
        *(i32x2*)&lds[((pt0 + 1) * 16 + n) * 38 + ot * 8 + g * 2] = w1;
    }
    __syncthreads();

    // ---- phase 2: kmap = W2*hid + b2 -> kls[j][px] bf16 ----
    const int* w2pk = (const int*)wpk + W2PK_OFF;
    for (int t = wid; t < 36; t += 8) {            // 9 j-tiles x 4 px-tiles
        const int jt = t >> 2, pt = t & 3;
        f32x4 acc = {0.f, 0.f, 0.f, 0.f};
        #pragma unroll
        for (int ks = 0; ks < 2; ++ks) {
            const int abase = jt * 1024 + ks * 512 + lane * 4;
            const i32x4 ah = *(const i32x4*)(w2pk + abase);
            const i32x4 al = *(const i32x4*)(w2pk + abase + 256);
            const int bb = (pt * 16 + n) * 38 + ks * 16 + g * 2;
            const i32x2 p0 = *(const i32x2*)&lds[bb];
            const i32x2 p1 = *(const i32x2*)&lds[bb + 8];
            const i32x4 bi = {p0.x, p0.y, p1.x, p1.y};
            const bf16x8 fb = as_bf16(bi);
            acc = __builtin_amdgcn_mfma_f32_16x16x32_bf16(as_bf16(ah), fb, acc, 0, 0, 0);
            acc = __builtin_amdgcn_mfma_f32_16x16x32_bf16(as_bf16(al), fb, acc, 0, 0, 0);
        }
        const f32x4 bs = *(const f32x4*)&b_span[jt * 16 + g * 4];
        const int jb = jt * 16 + g * 4;
        const int pxi = pt * 16 + n;
        lds_s[4864 + (jb + 0) * 66 + pxi] = (short)bf16_rne(acc.x + bs.x);
        lds_s[4864 + (jb + 1) * 66 + pxi] = (short)bf16_rne(acc.y + bs.y);
        lds_s[4864 + (jb + 2) * 66 + pxi] = (short)bf16_rne(acc.z + bs.z);
        lds_s[4864 + (jb + 3) * 66 + pxi] = (short)bf16_rne(acc.w + bs.w);
    }
    __syncthreads();

    // ---- apply: 32 channels (groups {2w,2w+1}) per wave, fp32 taps ----
    const bool vwm = (lane > 0), vwp = (lane < 63);
    const bool vhm = (hr  > 0), vhp = (hr  < 63);
    const bool vk[9] = { vhm && vwm, vhm, vhm && vwp,
                         vwm,        true, vwp,
                         vhp && vwm, vhp, vhp && vwp };
    float kv[18];
    #pragma unroll
    for (int jj = 0; jj < 18; ++jj) {
        const float v = bf16_f32((unsigned short)
                        lds_s[4864 + (wid * 18 + jj) * 66 + lane]);
        kv[jj] = vk[jj % 9] ? v : 0.f;
    }
    const int oWm = vwm ? -1  : 0, oWp = vwp ? 1  : 0;
    const int oHm = vhm ? -64 : 0, oHp = vhp ? 64 : 0;
    const int oo[9] = { oHm + oWm, oHm, oHm + oWp,
                        oWm,       0,   oWp,
                        oHp + oWm, oHp, oHp + oWp };

    const float* xrow = xb + lane;
    float*       orow = out + (size_t)b * (CCH * NHW) + hr * 64 + lane;

    #pragma unroll    // FULL unroll: gl, kv indices all compile-time (rule #20)
    for (int m = 0; m < 32; ++m) {
        const int c  = wid * 32 + m;
        const int gl = m >> 4;
        const float* xc = xrow + (size_t)c * NHW;
        float a = 0.f;
        #pragma unroll
        for (int k = 0; k < 9; ++k)
            a = fmaf(xc[oo[k]], kv[gl * 9 + k], a);
        orow[(size_t)c * NHW] = a;
    }
}

// ---------------------------------------------------------------------------
extern "C" void kernel_launch(void* const* d_in, const int* in_sizes, int n_in,
                              void* d_out, int out_size, void* d_ws, size_t ws_size,
                              hipStream_t stream) {
    const float* x        = (const float*)d_in[0];
    const float* w_reduce = (const float*)d_in[1];
    const float* b_reduce = (const float*)d_in[2];
    const float* w_span   = (const float*)d_in[3];
    const float* b_span   = (const float*)d_in[4];
    float* out = (float*)d_out;
    unsigned* ws = (unsigned*)d_ws;    // 100 KB used

    prepack_kernel<<<dim3(100), dim3(256), 0, stream>>>(w_reduce, w_span, ws);
    invol_fused<<<dim3(NB * 64), dim3(512), 0, stream>>>(
        x, b_reduce, b_span, ws, out);
}